// Round 16
// baseline (541.575 us; speedup 1.0000x reference)
//
#include <hip/hip_runtime.h>

#define NEG 0.2f
#define LOG2E 1.44269504088896f
typedef unsigned short u16;

__device__ __forceinline__ float sigmoidf_(float v){ return 1.f/(1.f+__expf(-v)); }
__device__ __forceinline__ int rfl_(int v){ return __builtin_amdgcn_readfirstlane(v); }
__device__ __forceinline__ float bf2f_(unsigned u){ return __uint_as_float(u<<16); }
__device__ __forceinline__ u16 f2bf_(float f){
  unsigned u = __float_as_uint(f);
  u += 0x7FFFu + ((u>>16)&1u);
  return (u16)(u>>16);
}
// 16-lane (head-group) sum via DPP row rotations: pure VALU, no DS pipe.
template<int C>
__device__ __forceinline__ float dppadd_(float p){
  int r = __builtin_amdgcn_update_dpp(0, __float_as_int(p), C, 0xF, 0xF, true);
  return p + __int_as_float(r);
}
__device__ __forceinline__ float dppsum16_(float p){
  p = dppadd_<0x121>(p);  // row_ror:1
  p = dppadd_<0x122>(p);  // row_ror:2
  p = dppadd_<0x124>(p);  // row_ror:4
  p = dppadd_<0x128>(p);  // row_ror:8
  return p;
}

// ---------------- degree count, x4/thread ----------------
__global__ void deg_kernel(const int* __restrict__ ei, int* __restrict__ deg, int E)
{
  int base = blockIdx.x*1024 + threadIdx.x;
  #pragma unroll
  for (int j=0;j<4;j++){
    int e = base + j*256;
    if (e < E) atomicAdd(deg + ei[E+e], 1);
  }
}

// ---------------- offset allocation: block-local scan + one atomic per block ----------------
__global__ __launch_bounds__(256) void alloc_kernel(
    const int* __restrict__ deg, int* __restrict__ offs, int* __restrict__ cursor,
    int* __restrict__ counter, int N)
{
  __shared__ int wsum[4], woff[4], sbase;
  int lane = threadIdx.x & 63, w = threadIdx.x >> 6;
  int base = blockIdx.x*1024 + threadIdx.x*4;
  int v[4]; int s=0;
  #pragma unroll
  for (int j=0;j<4;j++){ int i=base+j; v[j]=(i<N)?deg[i]:0; s+=v[j]; }
  int inc=s;
  #pragma unroll
  for (int d=1;d<64;d<<=1){ int t=__shfl_up(inc,d); if (lane>=d) inc+=t; }
  if (lane==63) wsum[w]=inc;
  __syncthreads();
  if (threadIdx.x==0){
    woff[0]=0; woff[1]=wsum[0]; woff[2]=wsum[0]+wsum[1]; woff[3]=wsum[0]+wsum[1]+wsum[2];
    sbase = atomicAdd(counter, woff[3]+wsum[3]);
  }
  __syncthreads();
  int excl = sbase + woff[w] + (inc - s);
  #pragma unroll
  for (int j=0;j<4;j++){
    int i=base+j;
    if (i<N){ offs[i]=excl; cursor[i]=excl; }
    excl+=v[j];
  }
}

// ---------------- fused: enc->xfrm1 (blocks [0,exB)) ∥ CSR slot fill x4 (rest) ----------------
// enc h stays in per-wave tiles (never materialized). All weights from global/L1
// so LDS stays 10.5KB and the fill role keeps full occupancy.
__global__ __launch_bounds__(256) void encxfill_kernel(
    const float* __restrict__ x, const float* __restrict__ pos,
    const int* __restrict__ ntype, const float* __restrict__ temb,
    const float* __restrict__ eW1, const float* __restrict__ eb1,
    const float* __restrict__ eW2, const float* __restrict__ eb2,
    const float* __restrict__ Wl, const float* __restrict__ bl,
    const float* __restrict__ Wr, const float* __restrict__ br,
    u16* __restrict__ xlo, u16* __restrict__ xro,
    const int* __restrict__ ei, const float* __restrict__ eattr,
    int* __restrict__ cursor, float4* __restrict__ slots,
    int exB, int E, int N)
{
  __shared__ float fT[4][8*20];
  __shared__ float tT[4][8*64];
  if ((int)blockIdx.x >= exB){
    int base = ((int)blockIdx.x - exB)*1024 + (int)threadIdx.x;
    #pragma unroll
    for (int j=0;j<4;j++){
      int e = base + j*256;
      if (e < E){
        int dst = ei[E + e];
        unsigned slot = (unsigned)atomicAdd(cursor + dst, 1);
        const float2* ep = (const float2*)(eattr + (size_t)e*6);
        float2 p0=ep[0], p1=ep[1], p2=ep[2];
        float4 a, b;
        a.x = __int_as_float(e); a.y = __int_as_float(ei[e]);
        a.z = p0.x; a.w = p0.y;
        b.x = p1.x; b.y = p1.y; b.z = p2.x; b.w = p2.y;
        slots[slot*2u]   = a;
        slots[slot*2u+1] = b;
      }
    }
    return;
  }
  int lane = threadIdx.x & 63;
  int wid  = threadIdx.x >> 6;
  int n0 = (blockIdx.x*4 + wid)*8;
  if (n0 >= N) return;
  #pragma unroll
  for (int m=0;m<8;m++){
    int n=n0+m; float fv=0.f;
    if (n<N){
      if (lane<7)       fv=x[(size_t)n*7+lane];
      else if (lane<10) fv=pos[(size_t)n*3+lane-7];
      else if (lane<18) fv=temb[ntype[n]*8+lane-10];
    }
    if (lane<20) fT[wid][m*20+lane]=fv;
  }
  float t[8];
  float b1v=eb1[lane];
  #pragma unroll
  for (int m=0;m<8;m++) t[m]=b1v;
  #pragma unroll 2
  for (int k=0;k<18;k++){
    float w=eW1[k*64+lane];
    #pragma unroll
    for (int m=0;m<8;m++) t[m] += fT[wid][m*20+k]*w;
  }
  #pragma unroll
  for (int m=0;m<8;m++){ t[m]=fmaxf(t[m],0.f); tT[wid][m*64+lane]=t[m]; }
  float o[8];
  float b2v=eb2[lane];
  #pragma unroll
  for (int m=0;m<8;m++) o[m]=b2v;
  #pragma unroll 2
  for (int k=0;k<64;k++){
    float w=eW2[k*64+lane];
    #pragma unroll
    for (int m=0;m<8;m++) o[m] += tT[wid][m*64+k]*w;
  }
  // restage h into the per-wave tile (wave-private, no barrier needed)
  #pragma unroll
  for (int m=0;m<8;m++) tT[wid][m*64+lane]=o[m];
  float blv=bl[lane], brv=br[lane];
  float al[8], ar[8];
  #pragma unroll
  for (int m=0;m<8;m++){ al[m]=blv; ar[m]=brv; }
  #pragma unroll 2
  for (int k=0;k<64;k++){
    float wl=Wl[k*64+lane], wr=Wr[k*64+lane];
    #pragma unroll
    for (int m=0;m<8;m++){
      float hb = tT[wid][m*64+k];
      al[m]+=hb*wl; ar[m]+=hb*wr;
    }
  }
  #pragma unroll
  for (int m=0;m<8;m++){
    int n=n0+m;
    if (n<N){ xlo[(((unsigned)n)<<6)+lane]=f2bf_(al[m]); xro[(((unsigned)n)<<6)+lane]=f2bf_(ar[m]); }
  }
}

// ---------------- xl = h@Wl+bl, xr = h@Wr+br -> bf16 (layer 2, LDS weights) ----------------
__global__ __launch_bounds__(256) void xfrm_kernel(
    const float* __restrict__ hin,
    const float* __restrict__ Wl, const float* __restrict__ bl,
    const float* __restrict__ Wr, const float* __restrict__ br,
    u16* __restrict__ xlo, u16* __restrict__ xro, int N)
{
  __shared__ float sWl[4096], sWr[4096];
  __shared__ float hT[4][16*64];
  for (int i=threadIdx.x;i<4096;i+=256){ sWl[i]=Wl[i]; sWr[i]=Wr[i]; }
  __syncthreads();
  int lane=threadIdx.x&63;
  int wid=threadIdx.x>>6;
  int n0=(blockIdx.x*4+wid)*16;
  if (n0>=N) return;
  #pragma unroll
  for (int m=0;m<16;m++){
    int n=n0+m;
    hT[wid][m*64+lane] = (n<N)? hin[(size_t)n*64+lane] : 0.f;
  }
  float blv=bl[lane], brv=br[lane];
  float al[16], ar[16];
  #pragma unroll
  for (int m=0;m<16;m++){ al[m]=blv; ar[m]=brv; }
  #pragma unroll 2
  for (int k=0;k<64;k++){
    float wl=sWl[k*64+lane], wr=sWr[k*64+lane];
    #pragma unroll
    for (int m=0;m<16;m++){
      float hb = hT[wid][m*64+k];
      al[m]+=hb*wl; ar[m]+=hb*wr;
    }
  }
  #pragma unroll
  for (int m=0;m<16;m++){
    int n=n0+m;
    if (n<N){ xlo[(((unsigned)n)<<6)+lane]=f2bf_(al[m]); xro[(((unsigned)n)<<6)+lane]=f2bf_(ar[m]); }
  }
}

// ---------------- fused GATv2 layer: wave per dst node, IN-KERNEL alpha finalize ----------------
// Pass 1: raw scores -> aout + online (m,s,acc). Pass 2 (L2-hot): final alpha in place.
#define EDGE_STEP(EIDX, EADD, XV) do {                                       \
    float s_ = (XV) + xrv + (EADD);                                          \
    s_ = fmaxf(s_, NEG*s_);                                                  \
    float p_ = dppsum16_(s_*attv);                                           \
    if (isbase) aout[(((unsigned)(EIDX))<<2)+h] = p_;                        \
    lastp = p_;                                                              \
    if (__all(p_ <= mmax)) {                                                 \
      float w_ = exp2f(p_ - mmax);                                           \
      ssum += w_; acc += w_*(XV);                                            \
    } else {                                                                 \
      float mn_ = fmaxf(mmax, p_);                                           \
      float sc_ = exp2f(mmax - mn_);                                         \
      float w_  = exp2f(p_ - mn_);                                           \
      ssum = ssum*sc_ + w_;                                                  \
      acc  = acc*sc_ + w_*(XV);                                              \
      mmax = mn_;                                                            \
    }                                                                        \
  } while(0)

#define EDGE_PRE(J, OO) \
    float4 u##J = slots[(unsigned)(OO)*2u], v##J = slots[(unsigned)(OO)*2u+1u]; \
    int e##J = rfl_(__float_as_int(u##J.x)); \
    int s##J = rfl_(__float_as_int(u##J.y)); \
    unsigned xv##J = xlb[(((unsigned)s##J)<<6)+lane];

#define EDGE_BODY(J) \
    float d##J = u##J.z*we0 + u##J.w*we1 + v##J.x*we2 + v##J.y*we3 + v##J.z*we4 + v##J.w*we5; \
    dsum += d##J; \
    EDGE_STEP(e##J, d##J, bf2f_(xv##J));

__global__ __launch_bounds__(256) void gat_kernel(
    const float4* __restrict__ slots, const int* __restrict__ offs, const int* __restrict__ deg,
    const u16* __restrict__ xlb, const u16* __restrict__ xrb,
    const float* __restrict__ We, const float* __restrict__ att,
    const float* __restrict__ bias,
    float* __restrict__ aout, float* __restrict__ hout,
    int E, int N, int do_relu)
{
  int lane = threadIdx.x & 63;
  int n = blockIdx.x*4 + (threadIdx.x>>6);
  if (n >= N) return;
  float we0=We[lane], we1=We[64+lane], we2=We[128+lane],
        we3=We[192+lane], we4=We[256+lane], we5=We[320+lane];
  float attv = att[lane] * LOG2E;       // log2 domain
  float bv = bias[lane];
  float xrv = bf2f_(xrb[(((unsigned)n)<<6)+lane]);
  int h = lane >> 4;
  bool isbase = (lane & 15) == 0;
  int o0 = rfl_(offs[n]);
  int dg = rfl_(deg[n]);
  int oend = o0 + dg;
  float mmax = -3.402823e38f, ssum=0.f, acc=0.f, dsum=0.f, lastp=0.f;
  int o = o0;
  for (; o+4 <= oend; o += 4){
    EDGE_PRE(0,o); EDGE_PRE(1,o+1); EDGE_PRE(2,o+2); EDGE_PRE(3,o+3);
    EDGE_BODY(0); EDGE_BODY(1); EDGE_BODY(2); EDGE_BODY(3);
  }
  for (; o < oend; ++o){
    EDGE_PRE(0,o);
    EDGE_BODY(0);
  }
  // self-loop (edge id E+n): ea@We term = mean of per-edge d terms (linearity)
  {
    float dS = dsum * (1.f/fmaxf((float)dg,1.f));
    float xvS = bf2f_((unsigned)xlb[(((unsigned)n)<<6)+lane]);
    EDGE_STEP(E+n, dS, xvS);
  }
  float sinv = 1.f/(ssum + 1e-16f);
  // ---- pass 2: finalize alpha in place (our own stores; L2-hot) ----
  asm volatile("s_waitcnt vmcnt(0)" ::: "memory");
  o = o0;
  for (; o+4 <= oend; o += 4){
    int e0 = __float_as_int(slots[(unsigned)o*2u].x);
    int e1 = __float_as_int(slots[(unsigned)(o+1)*2u].x);
    int e2 = __float_as_int(slots[(unsigned)(o+2)*2u].x);
    int e3 = __float_as_int(slots[(unsigned)(o+3)*2u].x);
    if (isbase){
      unsigned i0=(((unsigned)e0)<<2)+h, i1=(((unsigned)e1)<<2)+h,
               i2=(((unsigned)e2)<<2)+h, i3=(((unsigned)e3)<<2)+h;
      float r0=aout[i0], r1=aout[i1], r2=aout[i2], r3=aout[i3];
      aout[i0]=exp2f(r0-mmax)*sinv; aout[i1]=exp2f(r1-mmax)*sinv;
      aout[i2]=exp2f(r2-mmax)*sinv; aout[i3]=exp2f(r3-mmax)*sinv;
    }
  }
  for (; o < oend; ++o){
    int e0 = __float_as_int(slots[(unsigned)o*2u].x);
    if (isbase){
      unsigned i0=(((unsigned)e0)<<2)+h;
      aout[i0]=exp2f(aout[i0]-mmax)*sinv;
    }
  }
  if (isbase) aout[(((unsigned)(E+n))<<2)+h] = exp2f(lastp-mmax)*sinv;
  float outv = acc*sinv + bv;
  if (do_relu) outv = fmaxf(outv, 0.f);
  hout[(((unsigned)n)<<6)+lane] = outv;
}

// ---------------- GRU + decoder (standalone, 8 nodes per wave) ----------------
__global__ __launch_bounds__(256) void grudec_kernel(
    const float* __restrict__ h2, const float* __restrict__ hid,
    const float* __restrict__ Wi, const float* __restrict__ bi,
    const float* __restrict__ Wh, const float* __restrict__ bh,
    const int* __restrict__ Tptr,
    const float* __restrict__ W1, const float* __restrict__ b1,
    const float* __restrict__ W2, const float* __restrict__ b2,
    const float* __restrict__ x, const float* __restrict__ pos,
    float* __restrict__ nf, float* __restrict__ fout, int N)
{
  __shared__ float sW2[448];
  __shared__ float sb2[8];
  __shared__ float tT[4][8*68];
  __shared__ float pT[4][8*68];
  for (int i=threadIdx.x;i<448;i+=256) sW2[i]=W2[i];
  if (threadIdx.x<7)  sb2[threadIdx.x]=b2[threadIdx.x];
  __syncthreads();
  int lane = threadIdx.x & 63;
  int wid  = threadIdx.x >> 6;
  int n0 = (blockIdx.x*4 + wid)*8;
  if (n0 >= N) return;
  int T = *Tptr;
  float hv[8], nfv[8];
  #pragma unroll
  for (int m=0;m<8;m++){ int n=n0+m; hv[m] = (n<N)? h2[(size_t)n*64+lane] : 0.f; }
  if (n0 < T){
    float pv[8];
    #pragma unroll
    for (int m=0;m<8;m++){ int n=n0+m; pv[m] = (n<T)? hid[(size_t)n*64+lane] : 0.f; }
    #pragma unroll
    for (int m=0;m<8;m++){ tT[wid][m*68+lane]=hv[m]; pT[wid][m*68+lane]=pv[m]; }
    float gr[8],gz[8],gn[8],hr[8],hz[8],hn[8];
    #pragma unroll
    for (int m=0;m<8;m++){ gr[m]=0.f;gz[m]=0.f;gn[m]=0.f;hr[m]=0.f;hz[m]=0.f;hn[m]=0.f; }
    for (int k=0;k<64;k++){
      float wir=Wi[k*192+lane], wiz=Wi[k*192+64+lane], win=Wi[k*192+128+lane];
      float whr=Wh[k*192+lane], whz=Wh[k*192+64+lane], whn=Wh[k*192+128+lane];
      #pragma unroll
      for (int m=0;m<8;m++){
        float a=tT[wid][m*68+k], b=pT[wid][m*68+k];
        gr[m]+=a*wir; gz[m]+=a*wiz; gn[m]+=a*win;
        hr[m]+=b*whr; hz[m]+=b*whz; hn[m]+=b*whn;
      }
    }
    float bir=bi[lane], biz=bi[64+lane], bin=bi[128+lane];
    float bhr=bh[lane], bhz=bh[64+lane], bhn=bh[128+lane];
    #pragma unroll
    for (int m=0;m<8;m++){
      int n=n0+m;
      if (n<T){
        float r  = sigmoidf_(gr[m]+bir + hr[m]+bhr);
        float z  = sigmoidf_(gz[m]+biz + hz[m]+bhz);
        float nn = tanhf(gn[m]+bin + r*(hn[m]+bhn));
        nfv[m] = (1.f-z)*nn + z*pv[m];
      } else {
        nfv[m] = hv[m];
      }
    }
  } else {
    #pragma unroll
    for (int m=0;m<8;m++) nfv[m] = hv[m];
  }
  #pragma unroll
  for (int m=0;m<8;m++){ int n=n0+m; if (n<N) nf[(size_t)n*64+lane]=nfv[m]; }
  // ---- decoder stage 1: t = relu(nf@W1 + b1), W1 from global (L1-resident) ----
  #pragma unroll
  for (int m=0;m<8;m++) tT[wid][m*68+lane]=nfv[m];
  float t[8];
  float b1v=b1[lane];
  #pragma unroll
  for (int m=0;m<8;m++) t[m]=b1v;
  #pragma unroll 2
  for (int k=0;k<64;k++){
    float w=W1[k*64+lane];
    #pragma unroll
    for (int m=0;m<8;m++) t[m] += tT[wid][m*68+k]*w;
  }
  #pragma unroll
  for (int m=0;m<8;m++) t[m]=fmaxf(t[m],0.f);
  // ---- decoder stage 2: lane-parallel (node mm, col cc) dot over padded tile ----
  #pragma unroll
  for (int m=0;m<8;m++) tT[wid][m*68+lane]=t[m];
  int mm = lane >> 3, cc = lane & 7;
  if (cc < 7){
    float a2v = sb2[cc];
    #pragma unroll 4
    for (int k=0;k<64;k++) a2v += tT[wid][mm*68+k]*sW2[k*7+cc];
    int n = n0+mm;
    if (n < N){
      if (cc<3)      a2v += pos[(size_t)n*3+cc];
      else if (cc<6) a2v += x[(size_t)n*7+(cc-3)];
      fout[(size_t)n*7+cc] = a2v;
    }
  }
}

extern "C" void kernel_launch(void* const* d_in, const int* in_sizes, int n_in,
                              void* d_out, int out_size, void* d_ws, size_t ws_size,
                              hipStream_t stream)
{
  const float* x     = (const float*)d_in[0];
  const float* pos   = (const float*)d_in[1];
  const int*   ntype = (const int*)d_in[2];
  const int*   eidx  = (const int*)d_in[3];
  const float* eattr = (const float*)d_in[4];
  const int*   Tptr  = (const int*)d_in[5];
  const float* hid   = (const float*)d_in[6];
  const float* temb  = (const float*)d_in[7];
  const float* encW1 = (const float*)d_in[8];
  const float* encb1 = (const float*)d_in[9];
  const float* encW2 = (const float*)d_in[10];
  const float* encb2 = (const float*)d_in[11];
  const float* gruWi = (const float*)d_in[12];
  const float* grubi = (const float*)d_in[13];
  const float* gruWh = (const float*)d_in[14];
  const float* grubh = (const float*)d_in[15];
  const float* decW1 = (const float*)d_in[16];
  const float* decb1 = (const float*)d_in[17];
  const float* decW2 = (const float*)d_in[18];
  const float* decb2 = (const float*)d_in[19];
  const float* gWl[2]  = {(const float*)d_in[20], (const float*)d_in[27]};
  const float* gbl[2]  = {(const float*)d_in[21], (const float*)d_in[28]};
  const float* gWr[2]  = {(const float*)d_in[22], (const float*)d_in[29]};
  const float* gbr[2]  = {(const float*)d_in[23], (const float*)d_in[30]};
  const float* gWe[2]  = {(const float*)d_in[24], (const float*)d_in[31]};
  const float* gatt[2] = {(const float*)d_in[25], (const float*)d_in[32]};
  const float* gbias[2]= {(const float*)d_in[26], (const float*)d_in[33]};

  int N  = in_sizes[0] / 7;
  int E  = in_sizes[3] / 2;
  int Ea = E + N;

  char* w = (char*)d_ws;
  float* A      = (float*)w; w += (size_t)N*64*sizeof(float);   // h1 -> h2
  u16*   XL     = (u16*)w;  w += (size_t)N*64*sizeof(u16);
  u16*   XR     = (u16*)w;  w += (size_t)N*64*sizeof(u16);
  float4* slots = (float4*)w; w += (size_t)E*32;                // 32B per edge slot
  int*   deg    = (int*)w;   w += (size_t)N*sizeof(int);
  int*   counter= (int*)w;   w += 4*sizeof(int);
  int*   cursor = (int*)w;   w += (size_t)N*sizeof(int);
  int*   offs   = (int*)w;   w += (size_t)N*sizeof(int);

  float* out_final = (float*)d_out;
  float* out_nf    = out_final + (size_t)N*7;
  float* out_a1    = out_nf + (size_t)N*64;
  float* out_a2    = out_a1 + (size_t)Ea*4;

  // zero deg + counter (contiguous); cursor written by alloc_kernel
  hipMemsetAsync(deg, 0, ((size_t)N + 4)*sizeof(int), stream);

  deg_kernel<<<(E+1023)/1024, 256, 0, stream>>>(eidx, deg, E);
  alloc_kernel<<<(N+1023)/1024, 256, 0, stream>>>(deg, offs, cursor, counter, N);

  // enc->xfrm1 ∥ fill (enc-h never materialized)
  int exB = (N+31)/32;
  int flB = (E+1023)/1024;
  encxfill_kernel<<<exB+flB, 256, 0, stream>>>(x, pos, ntype, temb,
      encW1, encb1, encW2, encb2, gWl[0], gbl[0], gWr[0], gbr[0], XL, XR,
      eidx, eattr, cursor, slots, exB, E, N);

  // layer 1: gat (finalizes alpha1 in-kernel); out h1 -> A (relu)
  int gatB = (N+3)/4;
  gat_kernel<<<gatB, 256, 0, stream>>>(slots, offs, deg, XL, XR,
      gWe[0], gatt[0], gbias[0], out_a1, A, E, N, 1);

  // layer 2 xfrm (standalone, LDS weights)
  int xfB = (N+63)/64;
  xfrm_kernel<<<xfB, 256, 0, stream>>>(A, gWl[1], gbl[1], gWr[1], gbr[1], XL, XR, N);

  // layer 2: gat (finalizes alpha2 in-kernel); out h2 -> A (no relu)
  gat_kernel<<<gatB, 256, 0, stream>>>(slots, offs, deg, XL, XR,
      gWe[1], gatt[1], gbias[1], out_a2, A, E, N, 0);

  grudec_kernel<<<(N+31)/32, 256, 0, stream>>>(A, hid, gruWi, grubi, gruWh, grubh, Tptr,
      decW1, decb1, decW2, decb2, x, pos, out_nf, out_final, N);
}

// Round 17
// 495.320 us; speedup vs baseline: 1.0934x; 1.0934x over previous
//
#include <hip/hip_runtime.h>

#define NEG 0.2f
#define LOG2E 1.44269504088896f
typedef unsigned short u16;

__device__ __forceinline__ float sigmoidf_(float v){ return 1.f/(1.f+__expf(-v)); }
__device__ __forceinline__ int rfl_(int v){ return __builtin_amdgcn_readfirstlane(v); }
__device__ __forceinline__ float bf2f_(unsigned u){ return __uint_as_float(u<<16); }
__device__ __forceinline__ u16 f2bf_(float f){
  unsigned u = __float_as_uint(f);
  u += 0x7FFFu + ((u>>16)&1u);
  return (u16)(u>>16);
}
// 16-lane (head-group) sum via DPP row rotations: pure VALU, no DS pipe.
template<int C>
__device__ __forceinline__ float dppadd_(float p){
  int r = __builtin_amdgcn_update_dpp(0, __float_as_int(p), C, 0xF, 0xF, true);
  return p + __int_as_float(r);
}
__device__ __forceinline__ float dppsum16_(float p){
  p = dppadd_<0x121>(p);  // row_ror:1
  p = dppadd_<0x122>(p);  // row_ror:2
  p = dppadd_<0x124>(p);  // row_ror:4
  p = dppadd_<0x128>(p);  // row_ror:8
  return p;
}

// ---------------- degree count, x4/thread ----------------
__global__ void deg_kernel(const int* __restrict__ ei, int* __restrict__ deg, int E)
{
  int base = blockIdx.x*1024 + threadIdx.x;
  #pragma unroll
  for (int j=0;j<4;j++){
    int e = base + j*256;
    if (e < E) atomicAdd(deg + ei[E+e], 1);
  }
}

// ---------------- offset allocation: block-local scan + one atomic per block ----------------
__global__ __launch_bounds__(256) void alloc_kernel(
    const int* __restrict__ deg, int* __restrict__ offs, int* __restrict__ cursor,
    int* __restrict__ counter, int N)
{
  __shared__ int wsum[4], woff[4], sbase;
  int lane = threadIdx.x & 63, w = threadIdx.x >> 6;
  int base = blockIdx.x*1024 + threadIdx.x*4;
  int v[4]; int s=0;
  #pragma unroll
  for (int j=0;j<4;j++){ int i=base+j; v[j]=(i<N)?deg[i]:0; s+=v[j]; }
  int inc=s;
  #pragma unroll
  for (int d=1;d<64;d<<=1){ int t=__shfl_up(inc,d); if (lane>=d) inc+=t; }
  if (lane==63) wsum[w]=inc;
  __syncthreads();
  if (threadIdx.x==0){
    woff[0]=0; woff[1]=wsum[0]; woff[2]=wsum[0]+wsum[1]; woff[3]=wsum[0]+wsum[1]+wsum[2];
    sbase = atomicAdd(counter, woff[3]+wsum[3]);
  }
  __syncthreads();
  int excl = sbase + woff[w] + (inc - s);
  #pragma unroll
  for (int j=0;j<4;j++){
    int i=base+j;
    if (i<N){ offs[i]=excl; cursor[i]=excl; }
    excl+=v[j];
  }
}

// ---------------- fused: enc->xfrm1 (blocks [0,exB)) ∥ CSR slot fill x4 (rest) ----------------
// enc h stays in per-wave tiles (never materialized). All weights from global/L1
// so LDS stays 10.5KB and the fill role keeps full occupancy.
__global__ __launch_bounds__(256) void encxfill_kernel(
    const float* __restrict__ x, const float* __restrict__ pos,
    const int* __restrict__ ntype, const float* __restrict__ temb,
    const float* __restrict__ eW1, const float* __restrict__ eb1,
    const float* __restrict__ eW2, const float* __restrict__ eb2,
    const float* __restrict__ Wl, const float* __restrict__ bl,
    const float* __restrict__ Wr, const float* __restrict__ br,
    u16* __restrict__ xlo, u16* __restrict__ xro,
    const int* __restrict__ ei, const float* __restrict__ eattr,
    int* __restrict__ cursor, float4* __restrict__ slots,
    int exB, int E, int N)
{
  __shared__ float fT[4][8*20];
  __shared__ float tT[4][8*64];
  if ((int)blockIdx.x >= exB){
    int base = ((int)blockIdx.x - exB)*1024 + (int)threadIdx.x;
    #pragma unroll
    for (int j=0;j<4;j++){
      int e = base + j*256;
      if (e < E){
        int dst = ei[E + e];
        unsigned slot = (unsigned)atomicAdd(cursor + dst, 1);
        const float2* ep = (const float2*)(eattr + (size_t)e*6);
        float2 p0=ep[0], p1=ep[1], p2=ep[2];
        float4 a, b;
        a.x = __int_as_float(e); a.y = __int_as_float(ei[e]);
        a.z = p0.x; a.w = p0.y;
        b.x = p1.x; b.y = p1.y; b.z = p2.x; b.w = p2.y;
        slots[slot*2u]   = a;
        slots[slot*2u+1] = b;
      }
    }
    return;
  }
  int lane = threadIdx.x & 63;
  int wid  = threadIdx.x >> 6;
  int n0 = (blockIdx.x*4 + wid)*8;
  if (n0 >= N) return;
  #pragma unroll
  for (int m=0;m<8;m++){
    int n=n0+m; float fv=0.f;
    if (n<N){
      if (lane<7)       fv=x[(size_t)n*7+lane];
      else if (lane<10) fv=pos[(size_t)n*3+lane-7];
      else if (lane<18) fv=temb[ntype[n]*8+lane-10];
    }
    if (lane<20) fT[wid][m*20+lane]=fv;
  }
  float t[8];
  float b1v=eb1[lane];
  #pragma unroll
  for (int m=0;m<8;m++) t[m]=b1v;
  #pragma unroll 2
  for (int k=0;k<18;k++){
    float w=eW1[k*64+lane];
    #pragma unroll
    for (int m=0;m<8;m++) t[m] += fT[wid][m*20+k]*w;
  }
  #pragma unroll
  for (int m=0;m<8;m++){ t[m]=fmaxf(t[m],0.f); tT[wid][m*64+lane]=t[m]; }
  float o[8];
  float b2v=eb2[lane];
  #pragma unroll
  for (int m=0;m<8;m++) o[m]=b2v;
  #pragma unroll 2
  for (int k=0;k<64;k++){
    float w=eW2[k*64+lane];
    #pragma unroll
    for (int m=0;m<8;m++) o[m] += tT[wid][m*64+k]*w;
  }
  // restage h into the per-wave tile (wave-private, no barrier needed)
  #pragma unroll
  for (int m=0;m<8;m++) tT[wid][m*64+lane]=o[m];
  float blv=bl[lane], brv=br[lane];
  float al[8], ar[8];
  #pragma unroll
  for (int m=0;m<8;m++){ al[m]=blv; ar[m]=brv; }
  #pragma unroll 2
  for (int k=0;k<64;k++){
    float wl=Wl[k*64+lane], wr=Wr[k*64+lane];
    #pragma unroll
    for (int m=0;m<8;m++){
      float hb = tT[wid][m*64+k];
      al[m]+=hb*wl; ar[m]+=hb*wr;
    }
  }
  #pragma unroll
  for (int m=0;m<8;m++){
    int n=n0+m;
    if (n<N){ xlo[(((unsigned)n)<<6)+lane]=f2bf_(al[m]); xro[(((unsigned)n)<<6)+lane]=f2bf_(ar[m]); }
  }
}

// ---------------- xl = h@Wl+bl, xr = h@Wr+br -> bf16 (layer 2, LDS weights) ----------------
__global__ __launch_bounds__(256) void xfrm_kernel(
    const float* __restrict__ hin,
    const float* __restrict__ Wl, const float* __restrict__ bl,
    const float* __restrict__ Wr, const float* __restrict__ br,
    u16* __restrict__ xlo, u16* __restrict__ xro, int N)
{
  __shared__ float sWl[4096], sWr[4096];
  __shared__ float hT[4][16*64];
  for (int i=threadIdx.x;i<4096;i+=256){ sWl[i]=Wl[i]; sWr[i]=Wr[i]; }
  __syncthreads();
  int lane=threadIdx.x&63;
  int wid=threadIdx.x>>6;
  int n0=(blockIdx.x*4+wid)*16;
  if (n0>=N) return;
  #pragma unroll
  for (int m=0;m<16;m++){
    int n=n0+m;
    hT[wid][m*64+lane] = (n<N)? hin[(size_t)n*64+lane] : 0.f;
  }
  float blv=bl[lane], brv=br[lane];
  float al[16], ar[16];
  #pragma unroll
  for (int m=0;m<16;m++){ al[m]=blv; ar[m]=brv; }
  #pragma unroll 2
  for (int k=0;k<64;k++){
    float wl=sWl[k*64+lane], wr=sWr[k*64+lane];
    #pragma unroll
    for (int m=0;m<16;m++){
      float hb = hT[wid][m*64+k];
      al[m]+=hb*wl; ar[m]+=hb*wr;
    }
  }
  #pragma unroll
  for (int m=0;m<16;m++){
    int n=n0+m;
    if (n<N){ xlo[(((unsigned)n)<<6)+lane]=f2bf_(al[m]); xro[(((unsigned)n)<<6)+lane]=f2bf_(ar[m]); }
  }
}

// ---------------- fused GATv2 layer: wave per dst node, packed 32B slots (plain, msbuf out) ----------------
#define EDGE_STEP(EIDX, EADD, XV) do {                                       \
    float s_ = (XV) + xrv + (EADD);                                          \
    s_ = fmaxf(s_, NEG*s_);                                                  \
    float p_ = dppsum16_(s_*attv);                                           \
    if (isbase) aout[(((unsigned)(EIDX))<<2)+h] = p_;                        \
    if (__all(p_ <= mmax)) {                                                 \
      float w_ = exp2f(p_ - mmax);                                           \
      ssum += w_; acc += w_*(XV);                                            \
    } else {                                                                 \
      float mn_ = fmaxf(mmax, p_);                                           \
      float sc_ = exp2f(mmax - mn_);                                         \
      float w_  = exp2f(p_ - mn_);                                           \
      ssum = ssum*sc_ + w_;                                                  \
      acc  = acc*sc_ + w_*(XV);                                              \
      mmax = mn_;                                                            \
    }                                                                        \
  } while(0)

#define EDGE_PRE(J, OO) \
    float4 u##J = slots[(unsigned)(OO)*2u], v##J = slots[(unsigned)(OO)*2u+1u]; \
    int e##J = rfl_(__float_as_int(u##J.x)); \
    int s##J = rfl_(__float_as_int(u##J.y)); \
    unsigned xv##J = xlb[(((unsigned)s##J)<<6)+lane];

#define EDGE_BODY(J) \
    float d##J = u##J.z*we0 + u##J.w*we1 + v##J.x*we2 + v##J.y*we3 + v##J.z*we4 + v##J.w*we5; \
    dsum += d##J; \
    EDGE_STEP(e##J, d##J, bf2f_(xv##J));

__global__ __launch_bounds__(256) void gat_kernel(
    const float4* __restrict__ slots, const int* __restrict__ offs, const int* __restrict__ deg,
    const u16* __restrict__ xlb, const u16* __restrict__ xrb,
    const float* __restrict__ We, const float* __restrict__ att,
    const float* __restrict__ bias,
    float* __restrict__ aout, float2* __restrict__ msbuf,
    float* __restrict__ hout,
    int E, int N, int do_relu)
{
  int lane = threadIdx.x & 63;
  int n = blockIdx.x*4 + (threadIdx.x>>6);
  if (n >= N) return;
  float we0=We[lane], we1=We[64+lane], we2=We[128+lane],
        we3=We[192+lane], we4=We[256+lane], we5=We[320+lane];
  float attv = att[lane] * LOG2E;       // log2 domain
  float bv = bias[lane];
  float xrv = bf2f_(xrb[(((unsigned)n)<<6)+lane]);
  int h = lane >> 4;
  bool isbase = (lane & 15) == 0;
  int o0 = rfl_(offs[n]);
  int dg = rfl_(deg[n]);
  int oend = o0 + dg;
  float mmax = -3.402823e38f, ssum=0.f, acc=0.f, dsum=0.f;
  int o = o0;
  for (; o+4 <= oend; o += 4){
    EDGE_PRE(0,o); EDGE_PRE(1,o+1); EDGE_PRE(2,o+2); EDGE_PRE(3,o+3);
    EDGE_BODY(0); EDGE_BODY(1); EDGE_BODY(2); EDGE_BODY(3);
  }
  for (; o < oend; ++o){
    EDGE_PRE(0,o);
    EDGE_BODY(0);
  }
  // self-loop (edge id E+n): ea@We term = mean of per-edge d terms (linearity)
  {
    float dS = dsum * (1.f/fmaxf((float)dg,1.f));
    float xvS = bf2f_((unsigned)xlb[(((unsigned)n)<<6)+lane]);
    EDGE_STEP(E+n, dS, xvS);
  }
  float sinv = 1.f/(ssum + 1e-16f);
  if (isbase) msbuf[(((unsigned)n)<<2)+h] = make_float2(mmax, sinv);
  float outv = acc*sinv + bv;
  if (do_relu) outv = fmaxf(outv, 0.f);
  hout[(((unsigned)n)<<6)+lane] = outv;
}

// ---------------- alpha finalize: both layers in one coalesced pass, float4 I/O ----------------
__global__ void alpha_kernel(const int* __restrict__ ei,
                             const float2* __restrict__ ms1, const float2* __restrict__ ms2,
                             float4* __restrict__ a1, float4* __restrict__ a2, int E, int N)
{
  int e = blockIdx.x*256 + threadIdx.x;
  if (e >= E+N) return;
  int dst = (e<E)? ei[E+e] : (e-E);
  {
    float4 r = a1[e];
    const float2* mp = ms1 + (((unsigned)dst)<<2);
    float2 m0=mp[0], m1=mp[1], m2=mp[2], m3=mp[3];
    float4 o;
    o.x = exp2f(r.x - m0.x)*m0.y;
    o.y = exp2f(r.y - m1.x)*m1.y;
    o.z = exp2f(r.z - m2.x)*m2.y;
    o.w = exp2f(r.w - m3.x)*m3.y;
    a1[e] = o;
  }
  {
    float4 r = a2[e];
    const float2* mp = ms2 + (((unsigned)dst)<<2);
    float2 m0=mp[0], m1=mp[1], m2=mp[2], m3=mp[3];
    float4 o;
    o.x = exp2f(r.x - m0.x)*m0.y;
    o.y = exp2f(r.y - m1.x)*m1.y;
    o.z = exp2f(r.z - m2.x)*m2.y;
    o.w = exp2f(r.w - m3.x)*m3.y;
    a2[e] = o;
  }
}

// ---------------- GRU + decoder (standalone, 8 nodes per wave) ----------------
__global__ __launch_bounds__(256) void grudec_kernel(
    const float* __restrict__ h2, const float* __restrict__ hid,
    const float* __restrict__ Wi, const float* __restrict__ bi,
    const float* __restrict__ Wh, const float* __restrict__ bh,
    const int* __restrict__ Tptr,
    const float* __restrict__ W1, const float* __restrict__ b1,
    const float* __restrict__ W2, const float* __restrict__ b2,
    const float* __restrict__ x, const float* __restrict__ pos,
    float* __restrict__ nf, float* __restrict__ fout, int N)
{
  __shared__ float sW2[448];
  __shared__ float sb2[8];
  __shared__ float tT[4][8*68];
  __shared__ float pT[4][8*68];
  for (int i=threadIdx.x;i<448;i+=256) sW2[i]=W2[i];
  if (threadIdx.x<7)  sb2[threadIdx.x]=b2[threadIdx.x];
  __syncthreads();
  int lane = threadIdx.x & 63;
  int wid  = threadIdx.x >> 6;
  int n0 = (blockIdx.x*4 + wid)*8;
  if (n0 >= N) return;
  int T = *Tptr;
  float hv[8], nfv[8];
  #pragma unroll
  for (int m=0;m<8;m++){ int n=n0+m; hv[m] = (n<N)? h2[(size_t)n*64+lane] : 0.f; }
  if (n0 < T){
    float pv[8];
    #pragma unroll
    for (int m=0;m<8;m++){ int n=n0+m; pv[m] = (n<T)? hid[(size_t)n*64+lane] : 0.f; }
    #pragma unroll
    for (int m=0;m<8;m++){ tT[wid][m*68+lane]=hv[m]; pT[wid][m*68+lane]=pv[m]; }
    float gr[8],gz[8],gn[8],hr[8],hz[8],hn[8];
    #pragma unroll
    for (int m=0;m<8;m++){ gr[m]=0.f;gz[m]=0.f;gn[m]=0.f;hr[m]=0.f;hz[m]=0.f;hn[m]=0.f; }
    for (int k=0;k<64;k++){
      float wir=Wi[k*192+lane], wiz=Wi[k*192+64+lane], win=Wi[k*192+128+lane];
      float whr=Wh[k*192+lane], whz=Wh[k*192+64+lane], whn=Wh[k*192+128+lane];
      #pragma unroll
      for (int m=0;m<8;m++){
        float a=tT[wid][m*68+k], b=pT[wid][m*68+k];
        gr[m]+=a*wir; gz[m]+=a*wiz; gn[m]+=a*win;
        hr[m]+=b*whr; hz[m]+=b*whz; hn[m]+=b*whn;
      }
    }
    float bir=bi[lane], biz=bi[64+lane], bin=bi[128+lane];
    float bhr=bh[lane], bhz=bh[64+lane], bhn=bh[128+lane];
    #pragma unroll
    for (int m=0;m<8;m++){
      int n=n0+m;
      if (n<T){
        float r  = sigmoidf_(gr[m]+bir + hr[m]+bhr);
        float z  = sigmoidf_(gz[m]+biz + hz[m]+bhz);
        float nn = tanhf(gn[m]+bin + r*(hn[m]+bhn));
        nfv[m] = (1.f-z)*nn + z*pv[m];
      } else {
        nfv[m] = hv[m];
      }
    }
  } else {
    #pragma unroll
    for (int m=0;m<8;m++) nfv[m] = hv[m];
  }
  #pragma unroll
  for (int m=0;m<8;m++){ int n=n0+m; if (n<N) nf[(size_t)n*64+lane]=nfv[m]; }
  // ---- decoder stage 1: t = relu(nf@W1 + b1), W1 from global (L1-resident) ----
  #pragma unroll
  for (int m=0;m<8;m++) tT[wid][m*68+lane]=nfv[m];
  float t[8];
  float b1v=b1[lane];
  #pragma unroll
  for (int m=0;m<8;m++) t[m]=b1v;
  #pragma unroll 2
  for (int k=0;k<64;k++){
    float w=W1[k*64+lane];
    #pragma unroll
    for (int m=0;m<8;m++) t[m] += tT[wid][m*68+k]*w;
  }
  #pragma unroll
  for (int m=0;m<8;m++) t[m]=fmaxf(t[m],0.f);
  // ---- decoder stage 2: lane-parallel (node mm, col cc) dot over padded tile ----
  #pragma unroll
  for (int m=0;m<8;m++) tT[wid][m*68+lane]=t[m];
  int mm = lane >> 3, cc = lane & 7;
  if (cc < 7){
    float a2v = sb2[cc];
    #pragma unroll 4
    for (int k=0;k<64;k++) a2v += tT[wid][mm*68+k]*sW2[k*7+cc];
    int n = n0+mm;
    if (n < N){
      if (cc<3)      a2v += pos[(size_t)n*3+cc];
      else if (cc<6) a2v += x[(size_t)n*7+(cc-3)];
      fout[(size_t)n*7+cc] = a2v;
    }
  }
}

extern "C" void kernel_launch(void* const* d_in, const int* in_sizes, int n_in,
                              void* d_out, int out_size, void* d_ws, size_t ws_size,
                              hipStream_t stream)
{
  const float* x     = (const float*)d_in[0];
  const float* pos   = (const float*)d_in[1];
  const int*   ntype = (const int*)d_in[2];
  const int*   eidx  = (const int*)d_in[3];
  const float* eattr = (const float*)d_in[4];
  const int*   Tptr  = (const int*)d_in[5];
  const float* hid   = (const float*)d_in[6];
  const float* temb  = (const float*)d_in[7];
  const float* encW1 = (const float*)d_in[8];
  const float* encb1 = (const float*)d_in[9];
  const float* encW2 = (const float*)d_in[10];
  const float* encb2 = (const float*)d_in[11];
  const float* gruWi = (const float*)d_in[12];
  const float* grubi = (const float*)d_in[13];
  const float* gruWh = (const float*)d_in[14];
  const float* grubh = (const float*)d_in[15];
  const float* decW1 = (const float*)d_in[16];
  const float* decb1 = (const float*)d_in[17];
  const float* decW2 = (const float*)d_in[18];
  const float* decb2 = (const float*)d_in[19];
  const float* gWl[2]  = {(const float*)d_in[20], (const float*)d_in[27]};
  const float* gbl[2]  = {(const float*)d_in[21], (const float*)d_in[28]};
  const float* gWr[2]  = {(const float*)d_in[22], (const float*)d_in[29]};
  const float* gbr[2]  = {(const float*)d_in[23], (const float*)d_in[30]};
  const float* gWe[2]  = {(const float*)d_in[24], (const float*)d_in[31]};
  const float* gatt[2] = {(const float*)d_in[25], (const float*)d_in[32]};
  const float* gbias[2]= {(const float*)d_in[26], (const float*)d_in[33]};

  int N  = in_sizes[0] / 7;
  int E  = in_sizes[3] / 2;
  int Ea = E + N;

  char* w = (char*)d_ws;
  float* A      = (float*)w; w += (size_t)N*64*sizeof(float);   // h1 -> h2
  u16*   XL     = (u16*)w;  w += (size_t)N*64*sizeof(u16);
  u16*   XR     = (u16*)w;  w += (size_t)N*64*sizeof(u16);
  float2* msbuf1= (float2*)w; w += (size_t)N*4*sizeof(float2);
  float2* msbuf2= (float2*)w; w += (size_t)N*4*sizeof(float2);
  float4* slots = (float4*)w; w += (size_t)E*32;                // 32B per edge slot
  int*   deg    = (int*)w;   w += (size_t)N*sizeof(int);
  int*   counter= (int*)w;   w += 4*sizeof(int);
  int*   cursor = (int*)w;   w += (size_t)N*sizeof(int);
  int*   offs   = (int*)w;   w += (size_t)N*sizeof(int);

  float* out_final = (float*)d_out;
  float* out_nf    = out_final + (size_t)N*7;
  float* out_a1    = out_nf + (size_t)N*64;
  float* out_a2    = out_a1 + (size_t)Ea*4;

  // zero deg + counter (contiguous); cursor written by alloc_kernel
  hipMemsetAsync(deg, 0, ((size_t)N + 4)*sizeof(int), stream);

  deg_kernel<<<(E+1023)/1024, 256, 0, stream>>>(eidx, deg, E);
  alloc_kernel<<<(N+1023)/1024, 256, 0, stream>>>(deg, offs, cursor, counter, N);

  // enc->xfrm1 ∥ fill (enc-h never materialized)
  int exB = (N+31)/32;
  int flB = (E+1023)/1024;
  encxfill_kernel<<<exB+flB, 256, 0, stream>>>(x, pos, ntype, temb,
      encW1, encb1, encW2, encb2, gWl[0], gbl[0], gWr[0], gbr[0], XL, XR,
      eidx, eattr, cursor, slots, exB, E, N);

  // layer 1: gat; raw scores -> out_a1, (m,sinv) -> msbuf1; h1 -> A (relu)
  int gatB = (N+3)/4;
  gat_kernel<<<gatB, 256, 0, stream>>>(slots, offs, deg, XL, XR,
      gWe[0], gatt[0], gbias[0], out_a1, msbuf1, A, E, N, 1);

  // layer 2 xfrm (standalone, LDS weights)
  int xfB = (N+63)/64;
  xfrm_kernel<<<xfB, 256, 0, stream>>>(A, gWl[1], gbl[1], gWr[1], gbr[1], XL, XR, N);

  // layer 2: gat; raw scores -> out_a2, msbuf2; h2 -> A (no relu)
  gat_kernel<<<gatB, 256, 0, stream>>>(slots, offs, deg, XL, XR,
      gWe[1], gatt[1], gbias[1], out_a2, msbuf2, A, E, N, 0);

  // GRU + decoder
  grudec_kernel<<<(N+31)/32, 256, 0, stream>>>(A, hid, gruWi, grubi, gruWh, grubh, Tptr,
      decW1, decb1, decW2, decb2, x, pos, out_nf, out_final, N);

  // both alpha finalizations, coalesced
  alpha_kernel<<<(Ea+255)/256, 256, 0, stream>>>(eidx, msbuf1, msbuf2,
      (float4*)out_a1, (float4*)out_a2, E, N);
}

// Round 18
// 480.732 us; speedup vs baseline: 1.1266x; 1.0303x over previous
//
#include <hip/hip_runtime.h>

#define NEG 0.2f
#define LOG2E 1.44269504088896f
typedef unsigned short u16;

__device__ __forceinline__ float sigmoidf_(float v){ return 1.f/(1.f+__expf(-v)); }
__device__ __forceinline__ int rfl_(int v){ return __builtin_amdgcn_readfirstlane(v); }
__device__ __forceinline__ float bf2f_(unsigned u){ return __uint_as_float(u<<16); }
__device__ __forceinline__ u16 f2bf_(float f){
  unsigned u = __float_as_uint(f);
  u += 0x7FFFu + ((u>>16)&1u);
  return (u16)(u>>16);
}
// 16-lane (head-group) sum via DPP row rotations: pure VALU, no DS pipe.
template<int C>
__device__ __forceinline__ float dppadd_(float p){
  int r = __builtin_amdgcn_update_dpp(0, __float_as_int(p), C, 0xF, 0xF, true);
  return p + __int_as_float(r);
}
__device__ __forceinline__ float dppsum16_(float p){
  p = dppadd_<0x121>(p);  // row_ror:1
  p = dppadd_<0x122>(p);  // row_ror:2
  p = dppadd_<0x124>(p);  // row_ror:4
  p = dppadd_<0x128>(p);  // row_ror:8
  return p;
}

// single-layer alpha-finalize body, edge-parallel float4 (coalesced)
__device__ __forceinline__ void alpha_body_(int e, const int* __restrict__ ei,
    const float2* __restrict__ ms, float4* __restrict__ a, int E, int N)
{
  if (e >= E+N) return;
  int dst = (e<E)? ei[E+e] : (e-E);
  float4 r = a[e];
  const float2* mp = ms + (((unsigned)dst)<<2);
  float2 m0=mp[0], m1=mp[1], m2=mp[2], m3=mp[3];
  float4 o;
  o.x = exp2f(r.x - m0.x)*m0.y;
  o.y = exp2f(r.y - m1.x)*m1.y;
  o.z = exp2f(r.z - m2.x)*m2.y;
  o.w = exp2f(r.w - m3.x)*m3.y;
  a[e] = o;
}

// ---------------- degree count, x4/thread ----------------
__global__ void deg_kernel(const int* __restrict__ ei, int* __restrict__ deg, int E)
{
  int base = blockIdx.x*1024 + threadIdx.x;
  #pragma unroll
  for (int j=0;j<4;j++){
    int e = base + j*256;
    if (e < E) atomicAdd(deg + ei[E+e], 1);
  }
}

// ---------------- offset allocation: block-local scan + one atomic per block ----------------
__global__ __launch_bounds__(256) void alloc_kernel(
    const int* __restrict__ deg, int* __restrict__ offs, int* __restrict__ cursor,
    int* __restrict__ counter, int N)
{
  __shared__ int wsum[4], woff[4], sbase;
  int lane = threadIdx.x & 63, w = threadIdx.x >> 6;
  int base = blockIdx.x*1024 + threadIdx.x*4;
  int v[4]; int s=0;
  #pragma unroll
  for (int j=0;j<4;j++){ int i=base+j; v[j]=(i<N)?deg[i]:0; s+=v[j]; }
  int inc=s;
  #pragma unroll
  for (int d=1;d<64;d<<=1){ int t=__shfl_up(inc,d); if (lane>=d) inc+=t; }
  if (lane==63) wsum[w]=inc;
  __syncthreads();
  if (threadIdx.x==0){
    woff[0]=0; woff[1]=wsum[0]; woff[2]=wsum[0]+wsum[1]; woff[3]=wsum[0]+wsum[1]+wsum[2];
    sbase = atomicAdd(counter, woff[3]+wsum[3]);
  }
  __syncthreads();
  int excl = sbase + woff[w] + (inc - s);
  #pragma unroll
  for (int j=0;j<4;j++){
    int i=base+j;
    if (i<N){ offs[i]=excl; cursor[i]=excl; }
    excl+=v[j];
  }
}

// ---------------- fused: enc->xfrm1 (blocks [0,exB)) ∥ CSR slot fill x4 (rest) ----------------
// enc h stays in per-wave tiles (never materialized). All weights from global/L1
// so LDS stays 10.5KB and the fill role keeps full occupancy.
__global__ __launch_bounds__(256) void encxfill_kernel(
    const float* __restrict__ x, const float* __restrict__ pos,
    const int* __restrict__ ntype, const float* __restrict__ temb,
    const float* __restrict__ eW1, const float* __restrict__ eb1,
    const float* __restrict__ eW2, const float* __restrict__ eb2,
    const float* __restrict__ Wl, const float* __restrict__ bl,
    const float* __restrict__ Wr, const float* __restrict__ br,
    u16* __restrict__ xlo, u16* __restrict__ xro,
    const int* __restrict__ ei, const float* __restrict__ eattr,
    int* __restrict__ cursor, float4* __restrict__ slots,
    int exB, int E, int N)
{
  __shared__ float fT[4][8*20];
  __shared__ float tT[4][8*64];
  if ((int)blockIdx.x >= exB){
    int base = ((int)blockIdx.x - exB)*1024 + (int)threadIdx.x;
    #pragma unroll
    for (int j=0;j<4;j++){
      int e = base + j*256;
      if (e < E){
        int dst = ei[E + e];
        unsigned slot = (unsigned)atomicAdd(cursor + dst, 1);
        const float2* ep = (const float2*)(eattr + (size_t)e*6);
        float2 p0=ep[0], p1=ep[1], p2=ep[2];
        float4 a, b;
        a.x = __int_as_float(e); a.y = __int_as_float(ei[e]);
        a.z = p0.x; a.w = p0.y;
        b.x = p1.x; b.y = p1.y; b.z = p2.x; b.w = p2.y;
        slots[slot*2u]   = a;
        slots[slot*2u+1] = b;
      }
    }
    return;
  }
  int lane = threadIdx.x & 63;
  int wid  = threadIdx.x >> 6;
  int n0 = (blockIdx.x*4 + wid)*8;
  if (n0 >= N) return;
  #pragma unroll
  for (int m=0;m<8;m++){
    int n=n0+m; float fv=0.f;
    if (n<N){
      if (lane<7)       fv=x[(size_t)n*7+lane];
      else if (lane<10) fv=pos[(size_t)n*3+lane-7];
      else if (lane<18) fv=temb[ntype[n]*8+lane-10];
    }
    if (lane<20) fT[wid][m*20+lane]=fv;
  }
  float t[8];
  float b1v=eb1[lane];
  #pragma unroll
  for (int m=0;m<8;m++) t[m]=b1v;
  #pragma unroll 2
  for (int k=0;k<18;k++){
    float w=eW1[k*64+lane];
    #pragma unroll
    for (int m=0;m<8;m++) t[m] += fT[wid][m*20+k]*w;
  }
  #pragma unroll
  for (int m=0;m<8;m++){ t[m]=fmaxf(t[m],0.f); tT[wid][m*64+lane]=t[m]; }
  float o[8];
  float b2v=eb2[lane];
  #pragma unroll
  for (int m=0;m<8;m++) o[m]=b2v;
  #pragma unroll 2
  for (int k=0;k<64;k++){
    float w=eW2[k*64+lane];
    #pragma unroll
    for (int m=0;m<8;m++) o[m] += tT[wid][m*64+k]*w;
  }
  // restage h into the per-wave tile (wave-private, no barrier needed)
  #pragma unroll
  for (int m=0;m<8;m++) tT[wid][m*64+lane]=o[m];
  float blv=bl[lane], brv=br[lane];
  float al[8], ar[8];
  #pragma unroll
  for (int m=0;m<8;m++){ al[m]=blv; ar[m]=brv; }
  #pragma unroll 2
  for (int k=0;k<64;k++){
    float wl=Wl[k*64+lane], wr=Wr[k*64+lane];
    #pragma unroll
    for (int m=0;m<8;m++){
      float hb = tT[wid][m*64+k];
      al[m]+=hb*wl; ar[m]+=hb*wr;
    }
  }
  #pragma unroll
  for (int m=0;m<8;m++){
    int n=n0+m;
    if (n<N){ xlo[(((unsigned)n)<<6)+lane]=f2bf_(al[m]); xro[(((unsigned)n)<<6)+lane]=f2bf_(ar[m]); }
  }
}

// ---------------- xl = h@Wl+bl, xr = h@Wr+br -> bf16 (layer 2, LDS weights) ----------------
__global__ __launch_bounds__(256) void xfrm_kernel(
    const float* __restrict__ hin,
    const float* __restrict__ Wl, const float* __restrict__ bl,
    const float* __restrict__ Wr, const float* __restrict__ br,
    u16* __restrict__ xlo, u16* __restrict__ xro, int N)
{
  __shared__ float sWl[4096], sWr[4096];
  __shared__ float hT[4][16*64];
  for (int i=threadIdx.x;i<4096;i+=256){ sWl[i]=Wl[i]; sWr[i]=Wr[i]; }
  __syncthreads();
  int lane=threadIdx.x&63;
  int wid=threadIdx.x>>6;
  int n0=(blockIdx.x*4+wid)*16;
  if (n0>=N) return;
  #pragma unroll
  for (int m=0;m<16;m++){
    int n=n0+m;
    hT[wid][m*64+lane] = (n<N)? hin[(size_t)n*64+lane] : 0.f;
  }
  float blv=bl[lane], brv=br[lane];
  float al[16], ar[16];
  #pragma unroll
  for (int m=0;m<16;m++){ al[m]=blv; ar[m]=brv; }
  #pragma unroll 2
  for (int k=0;k<64;k++){
    float wl=sWl[k*64+lane], wr=sWr[k*64+lane];
    #pragma unroll
    for (int m=0;m<16;m++){
      float hb = hT[wid][m*64+k];
      al[m]+=hb*wl; ar[m]+=hb*wr;
    }
  }
  #pragma unroll
  for (int m=0;m<16;m++){
    int n=n0+m;
    if (n<N){ xlo[(((unsigned)n)<<6)+lane]=f2bf_(al[m]); xro[(((unsigned)n)<<6)+lane]=f2bf_(ar[m]); }
  }
}

// ---------------- GAT edge machinery ----------------
#define EDGE_STEP(EIDX, EADD, XV) do {                                       \
    float s_ = (XV) + xrv + (EADD);                                          \
    s_ = fmaxf(s_, NEG*s_);                                                  \
    float p_ = dppsum16_(s_*attv);                                           \
    if (isbase) aout[(((unsigned)(EIDX))<<2)+h] = p_;                        \
    if (__all(p_ <= mmax)) {                                                 \
      float w_ = exp2f(p_ - mmax);                                           \
      ssum += w_; acc += w_*(XV);                                            \
    } else {                                                                 \
      float mn_ = fmaxf(mmax, p_);                                           \
      float sc_ = exp2f(mmax - mn_);                                         \
      float w_  = exp2f(p_ - mn_);                                           \
      ssum = ssum*sc_ + w_;                                                  \
      acc  = acc*sc_ + w_*(XV);                                              \
      mmax = mn_;                                                            \
    }                                                                        \
  } while(0)

#define EDGE_PRE(J, OO) \
    float4 u##J = slots[(unsigned)(OO)*2u], v##J = slots[(unsigned)(OO)*2u+1u]; \
    int e##J = rfl_(__float_as_int(u##J.x)); \
    int s##J = rfl_(__float_as_int(u##J.y)); \
    unsigned xv##J = xlb[(((unsigned)s##J)<<6)+lane];

#define EDGE_BODY(J) \
    float d##J = u##J.z*we0 + u##J.w*we1 + v##J.x*we2 + v##J.y*we3 + v##J.z*we4 + v##J.w*we5; \
    dsum += d##J; \
    EDGE_STEP(e##J, d##J, bf2f_(xv##J));

__device__ __forceinline__ void gat_node_(int n,
    const float4* __restrict__ slots, const int* __restrict__ offs, const int* __restrict__ deg,
    const u16* __restrict__ xlb, const u16* __restrict__ xrb,
    const float* __restrict__ We, const float* __restrict__ att,
    const float* __restrict__ bias,
    float* __restrict__ aout, float2* __restrict__ msbuf,
    float* __restrict__ hout, int E, int N, int do_relu)
{
  int lane = threadIdx.x & 63;
  if (n >= N) return;
  float we0=We[lane], we1=We[64+lane], we2=We[128+lane],
        we3=We[192+lane], we4=We[256+lane], we5=We[320+lane];
  float attv = att[lane] * LOG2E;       // log2 domain
  float bv = bias[lane];
  float xrv = bf2f_(xrb[(((unsigned)n)<<6)+lane]);
  int h = lane >> 4;
  bool isbase = (lane & 15) == 0;
  int o0 = rfl_(offs[n]);
  int dg = rfl_(deg[n]);
  int oend = o0 + dg;
  float mmax = -3.402823e38f, ssum=0.f, acc=0.f, dsum=0.f;
  int o = o0;
  for (; o+4 <= oend; o += 4){
    EDGE_PRE(0,o); EDGE_PRE(1,o+1); EDGE_PRE(2,o+2); EDGE_PRE(3,o+3);
    EDGE_BODY(0); EDGE_BODY(1); EDGE_BODY(2); EDGE_BODY(3);
  }
  for (; o < oend; ++o){
    EDGE_PRE(0,o);
    EDGE_BODY(0);
  }
  // self-loop (edge id E+n): ea@We term = mean of per-edge d terms (linearity)
  {
    float dS = dsum * (1.f/fmaxf((float)dg,1.f));
    float xvS = bf2f_((unsigned)xlb[(((unsigned)n)<<6)+lane]);
    EDGE_STEP(E+n, dS, xvS);
  }
  float sinv = 1.f/(ssum + 1e-16f);
  if (isbase) msbuf[(((unsigned)n)<<2)+h] = make_float2(mmax, sinv);
  float outv = acc*sinv + bv;
  if (do_relu) outv = fmaxf(outv, 0.f);
  hout[(((unsigned)n)<<6)+lane] = outv;
}

// ---------------- gat layer 1 (plain) ----------------
__global__ __launch_bounds__(256) void gat_kernel(
    const float4* __restrict__ slots, const int* __restrict__ offs, const int* __restrict__ deg,
    const u16* __restrict__ xlb, const u16* __restrict__ xrb,
    const float* __restrict__ We, const float* __restrict__ att,
    const float* __restrict__ bias,
    float* __restrict__ aout, float2* __restrict__ msbuf,
    float* __restrict__ hout,
    int E, int N, int do_relu)
{
  int n = blockIdx.x*4 + (threadIdx.x>>6);
  gat_node_(n, slots, offs, deg, xlb, xrb, We, att, bias, aout, msbuf, hout, E, N, do_relu);
}

// ---------------- gat layer 2 with alpha1 guest blocks front-loaded [0,alB) ----------------
// gat is VALU-bound (92%) with 0 LDS: memory-bound alpha1 blocks fill its idle
// memory slots. alpha1 deps (out_a1/msbuf1) closed by gat1's dispatch.
__global__ __launch_bounds__(256) void gat2alpha_kernel(
    const float4* __restrict__ slots, const int* __restrict__ offs, const int* __restrict__ deg,
    const u16* __restrict__ xlb, const u16* __restrict__ xrb,
    const float* __restrict__ We, const float* __restrict__ att,
    const float* __restrict__ bias,
    float* __restrict__ aout, float2* __restrict__ msbuf,
    float* __restrict__ hout,
    const int* __restrict__ ei, const float2* __restrict__ ms1, float4* __restrict__ a1,
    int alB, int E, int N, int do_relu)
{
  int idx = blockIdx.x;
  if (idx < alB){
    alpha_body_(idx*256 + (int)threadIdx.x, ei, ms1, a1, E, N);
    return;
  }
  int n = (idx - alB)*4 + (threadIdx.x>>6);
  gat_node_(n, slots, offs, deg, xlb, xrb, We, att, bias, aout, msbuf, hout, E, N, do_relu);
}

// ---------------- fused: GRU+decoder (blocks [0,gdB)) ∥ alpha2 finalize (rest) ----------------
__global__ __launch_bounds__(256) void grudecalpha_kernel(
    const float* __restrict__ h2, const float* __restrict__ hid,
    const float* __restrict__ Wi, const float* __restrict__ bi,
    const float* __restrict__ Wh, const float* __restrict__ bh,
    const int* __restrict__ Tptr,
    const float* __restrict__ W1, const float* __restrict__ b1,
    const float* __restrict__ W2, const float* __restrict__ b2,
    const float* __restrict__ x, const float* __restrict__ pos,
    float* __restrict__ nf, float* __restrict__ fout,
    const int* __restrict__ ei,
    const float2* __restrict__ ms2, float4* __restrict__ a2,
    int gdB, int E, int N)
{
  __shared__ float sW2[448];
  __shared__ float sb2[8];
  __shared__ float tT[4][8*68];
  __shared__ float pT[4][8*68];
  if ((int)blockIdx.x >= gdB){
    int e = ((int)blockIdx.x - gdB)*256 + (int)threadIdx.x;
    alpha_body_(e, ei, ms2, a2, E, N);
    return;
  }
  for (int i=threadIdx.x;i<448;i+=256) sW2[i]=W2[i];
  if (threadIdx.x<7)  sb2[threadIdx.x]=b2[threadIdx.x];
  __syncthreads();
  int lane = threadIdx.x & 63;
  int wid  = threadIdx.x >> 6;
  int n0 = (blockIdx.x*4 + wid)*8;
  if (n0 >= N) return;
  int T = *Tptr;
  float hv[8], nfv[8];
  #pragma unroll
  for (int m=0;m<8;m++){ int n=n0+m; hv[m] = (n<N)? h2[(size_t)n*64+lane] : 0.f; }
  if (n0 < T){
    float pv[8];
    #pragma unroll
    for (int m=0;m<8;m++){ int n=n0+m; pv[m] = (n<T)? hid[(size_t)n*64+lane] : 0.f; }
    #pragma unroll
    for (int m=0;m<8;m++){ tT[wid][m*68+lane]=hv[m]; pT[wid][m*68+lane]=pv[m]; }
    float gr[8],gz[8],gn[8],hr[8],hz[8],hn[8];
    #pragma unroll
    for (int m=0;m<8;m++){ gr[m]=0.f;gz[m]=0.f;gn[m]=0.f;hr[m]=0.f;hz[m]=0.f;hn[m]=0.f; }
    for (int k=0;k<64;k++){
      float wir=Wi[k*192+lane], wiz=Wi[k*192+64+lane], win=Wi[k*192+128+lane];
      float whr=Wh[k*192+lane], whz=Wh[k*192+64+lane], whn=Wh[k*192+128+lane];
      #pragma unroll
      for (int m=0;m<8;m++){
        float a=tT[wid][m*68+k], b=pT[wid][m*68+k];
        gr[m]+=a*wir; gz[m]+=a*wiz; gn[m]+=a*win;
        hr[m]+=b*whr; hz[m]+=b*whz; hn[m]+=b*whn;
      }
    }
    float bir=bi[lane], biz=bi[64+lane], bin=bi[128+lane];
    float bhr=bh[lane], bhz=bh[64+lane], bhn=bh[128+lane];
    #pragma unroll
    for (int m=0;m<8;m++){
      int n=n0+m;
      if (n<T){
        float r  = sigmoidf_(gr[m]+bir + hr[m]+bhr);
        float z  = sigmoidf_(gz[m]+biz + hz[m]+bhz);
        float nn = tanhf(gn[m]+bin + r*(hn[m]+bhn));
        nfv[m] = (1.f-z)*nn + z*pv[m];
      } else {
        nfv[m] = hv[m];
      }
    }
  } else {
    #pragma unroll
    for (int m=0;m<8;m++) nfv[m] = hv[m];
  }
  #pragma unroll
  for (int m=0;m<8;m++){ int n=n0+m; if (n<N) nf[(size_t)n*64+lane]=nfv[m]; }
  // ---- decoder stage 1: t = relu(nf@W1 + b1), W1 from global (L1-resident) ----
  #pragma unroll
  for (int m=0;m<8;m++) tT[wid][m*68+lane]=nfv[m];
  float t[8];
  float b1v=b1[lane];
  #pragma unroll
  for (int m=0;m<8;m++) t[m]=b1v;
  #pragma unroll 2
  for (int k=0;k<64;k++){
    float w=W1[k*64+lane];
    #pragma unroll
    for (int m=0;m<8;m++) t[m] += tT[wid][m*68+k]*w;
  }
  #pragma unroll
  for (int m=0;m<8;m++) t[m]=fmaxf(t[m],0.f);
  // ---- decoder stage 2: lane-parallel (node mm, col cc) dot over padded tile ----
  #pragma unroll
  for (int m=0;m<8;m++) tT[wid][m*68+lane]=t[m];
  int mm = lane >> 3, cc = lane & 7;
  if (cc < 7){
    float a2v = sb2[cc];
    #pragma unroll 4
    for (int k=0;k<64;k++) a2v += tT[wid][mm*68+k]*sW2[k*7+cc];
    int n = n0+mm;
    if (n < N){
      if (cc<3)      a2v += pos[(size_t)n*3+cc];
      else if (cc<6) a2v += x[(size_t)n*7+(cc-3)];
      fout[(size_t)n*7+cc] = a2v;
    }
  }
}

extern "C" void kernel_launch(void* const* d_in, const int* in_sizes, int n_in,
                              void* d_out, int out_size, void* d_ws, size_t ws_size,
                              hipStream_t stream)
{
  const float* x     = (const float*)d_in[0];
  const float* pos   = (const float*)d_in[1];
  const int*   ntype = (const int*)d_in[2];
  const int*   eidx  = (const int*)d_in[3];
  const float* eattr = (const float*)d_in[4];
  const int*   Tptr  = (const int*)d_in[5];
  const float* hid   = (const float*)d_in[6];
  const float* temb  = (const float*)d_in[7];
  const float* encW1 = (const float*)d_in[8];
  const float* encb1 = (const float*)d_in[9];
  const float* encW2 = (const float*)d_in[10];
  const float* encb2 = (const float*)d_in[11];
  const float* gruWi = (const float*)d_in[12];
  const float* grubi = (const float*)d_in[13];
  const float* gruWh = (const float*)d_in[14];
  const float* grubh = (const float*)d_in[15];
  const float* decW1 = (const float*)d_in[16];
  const float* decb1 = (const float*)d_in[17];
  const float* decW2 = (const float*)d_in[18];
  const float* decb2 = (const float*)d_in[19];
  const float* gWl[2]  = {(const float*)d_in[20], (const float*)d_in[27]};
  const float* gbl[2]  = {(const float*)d_in[21], (const float*)d_in[28]};
  const float* gWr[2]  = {(const float*)d_in[22], (const float*)d_in[29]};
  const float* gbr[2]  = {(const float*)d_in[23], (const float*)d_in[30]};
  const float* gWe[2]  = {(const float*)d_in[24], (const float*)d_in[31]};
  const float* gatt[2] = {(const float*)d_in[25], (const float*)d_in[32]};
  const float* gbias[2]= {(const float*)d_in[26], (const float*)d_in[33]};

  int N  = in_sizes[0] / 7;
  int E  = in_sizes[3] / 2;
  int Ea = E + N;

  char* w = (char*)d_ws;
  float* A      = (float*)w; w += (size_t)N*64*sizeof(float);   // h1 -> h2
  u16*   XL     = (u16*)w;  w += (size_t)N*64*sizeof(u16);
  u16*   XR     = (u16*)w;  w += (size_t)N*64*sizeof(u16);
  float2* msbuf1= (float2*)w; w += (size_t)N*4*sizeof(float2);
  float2* msbuf2= (float2*)w; w += (size_t)N*4*sizeof(float2);
  float4* slots = (float4*)w; w += (size_t)E*32;                // 32B per edge slot
  int*   deg    = (int*)w;   w += (size_t)N*sizeof(int);
  int*   counter= (int*)w;   w += 4*sizeof(int);
  int*   cursor = (int*)w;   w += (size_t)N*sizeof(int);
  int*   offs   = (int*)w;   w += (size_t)N*sizeof(int);

  float* out_final = (float*)d_out;
  float* out_nf    = out_final + (size_t)N*7;
  float* out_a1    = out_nf + (size_t)N*64;
  float* out_a2    = out_a1 + (size_t)Ea*4;

  // zero deg + counter (contiguous); cursor written by alloc_kernel
  hipMemsetAsync(deg, 0, ((size_t)N + 4)*sizeof(int), stream);

  deg_kernel<<<(E+1023)/1024, 256, 0, stream>>>(eidx, deg, E);
  alloc_kernel<<<(N+1023)/1024, 256, 0, stream>>>(deg, offs, cursor, counter, N);

  // enc->xfrm1 ∥ fill (enc-h never materialized)
  int exB = (N+31)/32;
  int flB = (E+1023)/1024;
  encxfill_kernel<<<exB+flB, 256, 0, stream>>>(x, pos, ntype, temb,
      encW1, encb1, encW2, encb2, gWl[0], gbl[0], gWr[0], gbr[0], XL, XR,
      eidx, eattr, cursor, slots, exB, E, N);

  // layer 1: gat; raw scores -> out_a1, (m,sinv) -> msbuf1; h1 -> A (relu)
  int gatB = (N+3)/4;
  gat_kernel<<<gatB, 256, 0, stream>>>(slots, offs, deg, XL, XR,
      gWe[0], gatt[0], gbias[0], out_a1, msbuf1, A, E, N, 1);

  // layer 2 xfrm (standalone, LDS weights)
  int xfB = (N+63)/64;
  xfrm_kernel<<<xfB, 256, 0, stream>>>(A, gWl[1], gbl[1], gWr[1], gbr[1], XL, XR, N);

  // layer 2: gat ∥ alpha1 guest blocks (front-loaded)
  int alB = (Ea+255)/256;
  gat2alpha_kernel<<<alB+gatB, 256, 0, stream>>>(slots, offs, deg, XL, XR,
      gWe[1], gatt[1], gbias[1], out_a2, msbuf2, A,
      eidx, msbuf1, (float4*)out_a1, alB, E, N, 0);

  // GRU + decoder ∥ alpha2 (range-split)
  int gdB = (N+31)/32;
  grudecalpha_kernel<<<gdB+alB, 256, 0, stream>>>(A, hid, gruWi, grubi, gruWh, grubh, Tptr,
      decW1, decb1, decW2, decb2, x, pos, out_nf, out_final,
      eidx, msbuf2, (float4*)out_a2, gdB, E, N);
}

// Round 20
// 480.150 us; speedup vs baseline: 1.1279x; 1.0012x over previous
//
#include <hip/hip_runtime.h>

#define NEG 0.2f
#define LOG2E 1.44269504088896f
typedef unsigned short u16;

__device__ __forceinline__ float sigmoidf_(float v){ return 1.f/(1.f+__expf(-v)); }
__device__ __forceinline__ int rfl_(int v){ return __builtin_amdgcn_readfirstlane(v); }
__device__ __forceinline__ float bf2f_(unsigned u){ return __uint_as_float(u<<16); }
__device__ __forceinline__ u16 f2bf_(float f){
  unsigned u = __float_as_uint(f);
  u += 0x7FFFu + ((u>>16)&1u);
  return (u16)(u>>16);
}
// 16-lane (head-group) sum via DPP row rotations: pure VALU, no DS pipe.
// (builtin form: compiler handles the DPP read-after-write hazard wait states)
template<int C>
__device__ __forceinline__ float dppadd_(float p){
  int r = __builtin_amdgcn_update_dpp(0, __float_as_int(p), C, 0xF, 0xF, true);
  return p + __int_as_float(r);
}
__device__ __forceinline__ float dppsum16_(float p){
  p = dppadd_<0x121>(p);  // row_ror:1
  p = dppadd_<0x122>(p);  // row_ror:2
  p = dppadd_<0x124>(p);  // row_ror:4
  p = dppadd_<0x128>(p);  // row_ror:8
  return p;
}

// single-layer alpha-finalize body, edge-parallel float4 (coalesced)
__device__ __forceinline__ void alpha_body_(int e, const int* __restrict__ ei,
    const float2* __restrict__ ms, float4* __restrict__ a, int E, int N)
{
  if (e >= E+N) return;
  int dst = (e<E)? ei[E+e] : (e-E);
  float4 r = a[e];
  const float2* mp = ms + (((unsigned)dst)<<2);
  float2 m0=mp[0], m1=mp[1], m2=mp[2], m3=mp[3];
  float4 o;
  o.x = exp2f(r.x - m0.x)*m0.y;
  o.y = exp2f(r.y - m1.x)*m1.y;
  o.z = exp2f(r.z - m2.x)*m2.y;
  o.w = exp2f(r.w - m3.x)*m3.y;
  a[e] = o;
}

// ---------------- degree count, x4/thread ----------------
__global__ void deg_kernel(const int* __restrict__ ei, int* __restrict__ deg, int E)
{
  int base = blockIdx.x*1024 + threadIdx.x;
  #pragma unroll
  for (int j=0;j<4;j++){
    int e = base + j*256;
    if (e < E) atomicAdd(deg + ei[E+e], 1);
  }
}

// ---------------- offset allocation: block-local scan + one atomic per block ----------------
__global__ __launch_bounds__(256) void alloc_kernel(
    const int* __restrict__ deg, int* __restrict__ offs, int* __restrict__ cursor,
    int* __restrict__ counter, int N)
{
  __shared__ int wsum[4], woff[4], sbase;
  int lane = threadIdx.x & 63, w = threadIdx.x >> 6;
  int base = blockIdx.x*1024 + threadIdx.x*4;
  int v[4]; int s=0;
  #pragma unroll
  for (int j=0;j<4;j++){ int i=base+j; v[j]=(i<N)?deg[i]:0; s+=v[j]; }
  int inc=s;
  #pragma unroll
  for (int d=1;d<64;d<<=1){ int t=__shfl_up(inc,d); if (lane>=d) inc+=t; }
  if (lane==63) wsum[w]=inc;
  __syncthreads();
  if (threadIdx.x==0){
    woff[0]=0; woff[1]=wsum[0]; woff[2]=wsum[0]+wsum[1]; woff[3]=wsum[0]+wsum[1]+wsum[2];
    sbase = atomicAdd(counter, woff[3]+wsum[3]);
  }
  __syncthreads();
  int excl = sbase + woff[w] + (inc - s);
  #pragma unroll
  for (int j=0;j<4;j++){
    int i=base+j;
    if (i<N){ offs[i]=excl; cursor[i]=excl; }
    excl+=v[j];
  }
}

// ---------------- fused: enc->xfrm1 (blocks [0,exB)) ∥ CSR slot fill x4 (rest) ----------------
__global__ __launch_bounds__(256) void encxfill_kernel(
    const float* __restrict__ x, const float* __restrict__ pos,
    const int* __restrict__ ntype, const float* __restrict__ temb,
    const float* __restrict__ eW1, const float* __restrict__ eb1,
    const float* __restrict__ eW2, const float* __restrict__ eb2,
    const float* __restrict__ Wl, const float* __restrict__ bl,
    const float* __restrict__ Wr, const float* __restrict__ br,
    u16* __restrict__ xlo, u16* __restrict__ xro,
    const int* __restrict__ ei, const float* __restrict__ eattr,
    int* __restrict__ cursor, float4* __restrict__ slots,
    int exB, int E, int N)
{
  __shared__ float fT[4][8*20];
  __shared__ float tT[4][8*64];
  if ((int)blockIdx.x >= exB){
    int base = ((int)blockIdx.x - exB)*1024 + (int)threadIdx.x;
    #pragma unroll
    for (int j=0;j<4;j++){
      int e = base + j*256;
      if (e < E){
        int dst = ei[E + e];
        unsigned slot = (unsigned)atomicAdd(cursor + dst, 1);
        const float2* ep = (const float2*)(eattr + (size_t)e*6);
        float2 p0=ep[0], p1=ep[1], p2=ep[2];
        float4 a, b;
        a.x = __int_as_float(e); a.y = __int_as_float(ei[e]);
        a.z = p0.x; a.w = p0.y;
        b.x = p1.x; b.y = p1.y; b.z = p2.x; b.w = p2.y;
        slots[slot*2u]   = a;
        slots[slot*2u+1] = b;
      }
    }
    return;
  }
  int lane = threadIdx.x & 63;
  int wid  = threadIdx.x >> 6;
  int n0 = (blockIdx.x*4 + wid)*8;
  if (n0 >= N) return;
  #pragma unroll
  for (int m=0;m<8;m++){
    int n=n0+m; float fv=0.f;
    if (n<N){
      if (lane<7)       fv=x[(size_t)n*7+lane];
      else if (lane<10) fv=pos[(size_t)n*3+lane-7];
      else if (lane<18) fv=temb[ntype[n]*8+lane-10];
    }
    if (lane<20) fT[wid][m*20+lane]=fv;
  }
  float t[8];
  float b1v=eb1[lane];
  #pragma unroll
  for (int m=0;m<8;m++) t[m]=b1v;
  #pragma unroll 2
  for (int k=0;k<18;k++){
    float w=eW1[k*64+lane];
    #pragma unroll
    for (int m=0;m<8;m++) t[m] += fT[wid][m*20+k]*w;
  }
  #pragma unroll
  for (int m=0;m<8;m++){ t[m]=fmaxf(t[m],0.f); tT[wid][m*64+lane]=t[m]; }
  float o[8];
  float b2v=eb2[lane];
  #pragma unroll
  for (int m=0;m<8;m++) o[m]=b2v;
  #pragma unroll 2
  for (int k=0;k<64;k++){
    float w=eW2[k*64+lane];
    #pragma unroll
    for (int m=0;m<8;m++) o[m] += tT[wid][m*64+k]*w;
  }
  // restage h into the per-wave tile (wave-private, no barrier needed)
  #pragma unroll
  for (int m=0;m<8;m++) tT[wid][m*64+lane]=o[m];
  float blv=bl[lane], brv=br[lane];
  float al[8], ar[8];
  #pragma unroll
  for (int m=0;m<8;m++){ al[m]=blv; ar[m]=brv; }
  #pragma unroll 2
  for (int k=0;k<64;k++){
    float wl=Wl[k*64+lane], wr=Wr[k*64+lane];
    #pragma unroll
    for (int m=0;m<8;m++){
      float hb = tT[wid][m*64+k];
      al[m]+=hb*wl; ar[m]+=hb*wr;
    }
  }
  #pragma unroll
  for (int m=0;m<8;m++){
    int n=n0+m;
    if (n<N){ xlo[(((unsigned)n)<<6)+lane]=f2bf_(al[m]); xro[(((unsigned)n)<<6)+lane]=f2bf_(ar[m]); }
  }
}

// ---------------- xl = h@Wl+bl, xr = h@Wr+br -> bf16 (layer 2, LDS weights) ----------------
__global__ __launch_bounds__(256) void xfrm_kernel(
    const float* __restrict__ hin,
    const float* __restrict__ Wl, const float* __restrict__ bl,
    const float* __restrict__ Wr, const float* __restrict__ br,
    u16* __restrict__ xlo, u16* __restrict__ xro, int N)
{
  __shared__ float sWl[4096], sWr[4096];
  __shared__ float hT[4][16*64];
  for (int i=threadIdx.x;i<4096;i+=256){ sWl[i]=Wl[i]; sWr[i]=Wr[i]; }
  __syncthreads();
  int lane=threadIdx.x&63;
  int wid=threadIdx.x>>6;
  int n0=(blockIdx.x*4+wid)*16;
  if (n0>=N) return;
  #pragma unroll
  for (int m=0;m<16;m++){
    int n=n0+m;
    hT[wid][m*64+lane] = (n<N)? hin[(size_t)n*64+lane] : 0.f;
  }
  float blv=bl[lane], brv=br[lane];
  float al[16], ar[16];
  #pragma unroll
  for (int m=0;m<16;m++){ al[m]=blv; ar[m]=brv; }
  #pragma unroll 2
  for (int k=0;k<64;k++){
    float wl=sWl[k*64+lane], wr=sWr[k*64+lane];
    #pragma unroll
    for (int m=0;m<16;m++){
      float hb = hT[wid][m*64+k];
      al[m]+=hb*wl; ar[m]+=hb*wr;
    }
  }
  #pragma unroll
  for (int m=0;m<16;m++){
    int n=n0+m;
    if (n<N){ xlo[(((unsigned)n)<<6)+lane]=f2bf_(al[m]); xro[(((unsigned)n)<<6)+lane]=f2bf_(ar[m]); }
  }
}

// ---------------- GAT edge machinery ----------------
#define EDGE_STEP(EIDX, EADD, XV) do {                                       \
    float s_ = (XV) + xrv + (EADD);                                          \
    s_ = fmaxf(s_, NEG*s_);                                                  \
    float p_ = dppsum16_(s_*attv);                                           \
    if (isbase) aout[(((unsigned)(EIDX))<<2)+h] = p_;                        \
    if (__all(p_ <= mmax)) {                                                 \
      float w_ = exp2f(p_ - mmax);                                           \
      ssum += w_; acc += w_*(XV);                                            \
    } else {                                                                 \
      float mn_ = fmaxf(mmax, p_);                                           \
      float sc_ = exp2f(mmax - mn_);                                         \
      float w_  = exp2f(p_ - mn_);                                           \
      ssum = ssum*sc_ + w_;                                                  \
      acc  = acc*sc_ + w_*(XV);                                              \
      mmax = mn_;                                                            \
    }                                                                        \
  } while(0)

#define EDGE_PRE(J, OO) \
    float4 u##J = slots[(unsigned)(OO)*2u], v##J = slots[(unsigned)(OO)*2u+1u]; \
    int e##J = rfl_(__float_as_int(u##J.x)); \
    int s##J = rfl_(__float_as_int(u##J.y)); \
    unsigned xv##J = xlb[(((unsigned)s##J)<<6)+lane];

#define EDGE_BODY(J) \
    float d##J = u##J.z*we0 + u##J.w*we1 + v##J.x*we2 + v##J.y*we3 + v##J.z*we4 + v##J.w*we5; \
    dsum += d##J; \
    EDGE_STEP(e##J, d##J, bf2f_(xv##J));

__device__ __forceinline__ void gat_node_(int n,
    const float4* __restrict__ slots, const int* __restrict__ offs, const int* __restrict__ deg,
    const u16* __restrict__ xlb, const u16* __restrict__ xrb,
    const float* __restrict__ We, const float* __restrict__ att,
    const float* __restrict__ bias,
    float* __restrict__ aout, float2* __restrict__ msbuf,
    float* __restrict__ hout, int E, int N, int do_relu)
{
  int lane = threadIdx.x & 63;
  if (n >= N) return;
  float we0=We[lane], we1=We[64+lane], we2=We[128+lane],
        we3=We[192+lane], we4=We[256+lane], we5=We[320+lane];
  float attv = att[lane] * LOG2E;       // log2 domain
  float bv = bias[lane];
  float xrv = bf2f_(xrb[(((unsigned)n)<<6)+lane]);
  int h = lane >> 4;
  bool isbase = (lane & 15) == 0;
  int o0 = rfl_(offs[n]);
  int dg = rfl_(deg[n]);
  int oend = o0 + dg;
  float mmax = -3.402823e38f, ssum=0.f, acc=0.f, dsum=0.f;
  int o = o0;
  for (; o+4 <= oend; o += 4){
    EDGE_PRE(0,o); EDGE_PRE(1,o+1); EDGE_PRE(2,o+2); EDGE_PRE(3,o+3);
    EDGE_BODY(0); EDGE_BODY(1); EDGE_BODY(2); EDGE_BODY(3);
  }
  for (; o < oend; ++o){
    EDGE_PRE(0,o);
    EDGE_BODY(0);
  }
  // self-loop (edge id E+n): ea@We term = mean of per-edge d terms (linearity)
  {
    float dS = dsum * (1.f/fmaxf((float)dg,1.f));
    float xvS = bf2f_((unsigned)xlb[(((unsigned)n)<<6)+lane]);
    EDGE_STEP(E+n, dS, xvS);
  }
  float sinv = 1.f/(ssum + 1e-16f);
  if (isbase) msbuf[(((unsigned)n)<<2)+h] = make_float2(mmax, sinv);
  float outv = acc*sinv + bv;
  if (do_relu) outv = fmaxf(outv, 0.f);
  hout[(((unsigned)n)<<6)+lane] = outv;
}

// ---------------- gat layer 1 (plain) ----------------
__global__ __launch_bounds__(256) void gat_kernel(
    const float4* __restrict__ slots, const int* __restrict__ offs, const int* __restrict__ deg,
    const u16* __restrict__ xlb, const u16* __restrict__ xrb,
    const float* __restrict__ We, const float* __restrict__ att,
    const float* __restrict__ bias,
    float* __restrict__ aout, float2* __restrict__ msbuf,
    float* __restrict__ hout,
    int E, int N, int do_relu)
{
  int n = blockIdx.x*4 + (threadIdx.x>>6);
  gat_node_(n, slots, offs, deg, xlb, xrb, We, att, bias, aout, msbuf, hout, E, N, do_relu);
}

// ---------------- gat layer 2 with alpha1 guest blocks front-loaded [0,alB) ----------------
__global__ __launch_bounds__(256) void gat2alpha_kernel(
    const float4* __restrict__ slots, const int* __restrict__ offs, const int* __restrict__ deg,
    const u16* __restrict__ xlb, const u16* __restrict__ xrb,
    const float* __restrict__ We, const float* __restrict__ att,
    const float* __restrict__ bias,
    float* __restrict__ aout, float2* __restrict__ msbuf,
    float* __restrict__ hout,
    const int* __restrict__ ei, const float2* __restrict__ ms1, float4* __restrict__ a1,
    int alB, int E, int N, int do_relu)
{
  int idx = blockIdx.x;
  if (idx < alB){
    alpha_body_(idx*256 + (int)threadIdx.x, ei, ms1, a1, E, N);
    return;
  }
  int n = (idx - alB)*4 + (threadIdx.x>>6);
  gat_node_(n, slots, offs, deg, xlb, xrb, We, att, bias, aout, msbuf, hout, E, N, do_relu);
}

// ---------------- fused: GRU+decoder (blocks [0,gdB)) ∥ alpha2 finalize (rest) ----------------
__global__ __launch_bounds__(256) void grudecalpha_kernel(
    const float* __restrict__ h2, const float* __restrict__ hid,
    const float* __restrict__ Wi, const float* __restrict__ bi,
    const float* __restrict__ Wh, const float* __restrict__ bh,
    const int* __restrict__ Tptr,
    const float* __restrict__ W1, const float* __restrict__ b1,
    const float* __restrict__ W2, const float* __restrict__ b2,
    const float* __restrict__ x, const float* __restrict__ pos,
    float* __restrict__ nf, float* __restrict__ fout,
    const int* __restrict__ ei,
    const float2* __restrict__ ms2, float4* __restrict__ a2,
    int gdB, int E, int N)
{
  __shared__ float sW2[448];
  __shared__ float sb2[8];
  __shared__ float tT[4][8*68];
  __shared__ float pT[4][8*68];
  if ((int)blockIdx.x >= gdB){
    int e = ((int)blockIdx.x - gdB)*256 + (int)threadIdx.x;
    alpha_body_(e, ei, ms2, a2, E, N);
    return;
  }
  for (int i=threadIdx.x;i<448;i+=256) sW2[i]=W2[i];
  if (threadIdx.x<7)  sb2[threadIdx.x]=b2[threadIdx.x];
  __syncthreads();
  int lane = threadIdx.x & 63;
  int wid  = threadIdx.x >> 6;
  int n0 = (blockIdx.x*4 + wid)*8;
  if (n0 >= N) return;
  int T = *Tptr;
  float hv[8], nfv[8];
  #pragma unroll
  for (int m=0;m<8;m++){ int n=n0+m; hv[m] = (n<N)? h2[(size_t)n*64+lane] : 0.f; }
  if (n0 < T){
    float pv[8];
    #pragma unroll
    for (int m=0;m<8;m++){ int n=n0+m; pv[m] = (n<T)? hid[(size_t)n*64+lane] : 0.f; }
    #pragma unroll
    for (int m=0;m<8;m++){ tT[wid][m*68+lane]=hv[m]; pT[wid][m*68+lane]=pv[m]; }
    float gr[8],gz[8],gn[8],hr[8],hz[8],hn[8];
    #pragma unroll
    for (int m=0;m<8;m++){ gr[m]=0.f;gz[m]=0.f;gn[m]=0.f;hr[m]=0.f;hz[m]=0.f;hn[m]=0.f; }
    for (int k=0;k<64;k++){
      float wir=Wi[k*192+lane], wiz=Wi[k*192+64+lane], win=Wi[k*192+128+lane];
      float whr=Wh[k*192+lane], whz=Wh[k*192+64+lane], whn=Wh[k*192+128+lane];
      #pragma unroll
      for (int m=0;m<8;m++){
        float a=tT[wid][m*68+k], b=pT[wid][m*68+k];
        gr[m]+=a*wir; gz[m]+=a*wiz; gn[m]+=a*win;
        hr[m]+=b*whr; hz[m]+=b*whz; hn[m]+=b*whn;
      }
    }
    float bir=bi[lane], biz=bi[64+lane], bin=bi[128+lane];
    float bhr=bh[lane], bhz=bh[64+lane], bhn=bh[128+lane];
    #pragma unroll
    for (int m=0;m<8;m++){
      int n=n0+m;
      if (n<T){
        float r  = sigmoidf_(gr[m]+bir + hr[m]+bhr);
        float z  = sigmoidf_(gz[m]+biz + hz[m]+bhz);
        float nn = tanhf(gn[m]+bin + r*(hn[m]+bhn));
        nfv[m] = (1.f-z)*nn + z*pv[m];
      } else {
        nfv[m] = hv[m];
      }
    }
  } else {
    #pragma unroll
    for (int m=0;m<8;m++) nfv[m] = hv[m];
  }
  #pragma unroll
  for (int m=0;m<8;m++){ int n=n0+m; if (n<N) nf[(size_t)n*64+lane]=nfv[m]; }
  // ---- decoder stage 1: t = relu(nf@W1 + b1), W1 from global (L1-resident) ----
  #pragma unroll
  for (int m=0;m<8;m++) tT[wid][m*68+lane]=nfv[m];
  float t[8];
  float b1v=b1[lane];
  #pragma unroll
  for (int m=0;m<8;m++) t[m]=b1v;
  #pragma unroll 2
  for (int k=0;k<64;k++){
    float w=W1[k*64+lane];
    #pragma unroll
    for (int m=0;m<8;m++) t[m] += tT[wid][m*68+k]*w;
  }
  #pragma unroll
  for (int m=0;m<8;m++) t[m]=fmaxf(t[m],0.f);
  // ---- decoder stage 2: lane-parallel (node mm, col cc) dot over padded tile ----
  #pragma unroll
  for (int m=0;m<8;m++) tT[wid][m*68+lane]=t[m];
  int mm = lane >> 3, cc = lane & 7;
  if (cc < 7){
    float a2v = sb2[cc];
    #pragma unroll 4
    for (int k=0;k<64;k++) a2v += tT[wid][mm*68+k]*sW2[k*7+cc];
    int n = n0+mm;
    if (n < N){
      if (cc<3)      a2v += pos[(size_t)n*3+cc];
      else if (cc<6) a2v += x[(size_t)n*7+(cc-3)];
      fout[(size_t)n*7+cc] = a2v;
    }
  }
}

extern "C" void kernel_launch(void* const* d_in, const int* in_sizes, int n_in,
                              void* d_out, int out_size, void* d_ws, size_t ws_size,
                              hipStream_t stream)
{
  const float* x     = (const float*)d_in[0];
  const float* pos   = (const float*)d_in[1];
  const int*   ntype = (const int*)d_in[2];
  const int*   eidx  = (const int*)d_in[3];
  const float* eattr = (const float*)d_in[4];
  const int*   Tptr  = (const int*)d_in[5];
  const float* hid   = (const float*)d_in[6];
  const float* temb  = (const float*)d_in[7];
  const float* encW1 = (const float*)d_in[8];
  const float* encb1 = (const float*)d_in[9];
  const float* encW2 = (const float*)d_in[10];
  const float* encb2 = (const float*)d_in[11];
  const float* gruWi = (const float*)d_in[12];
  const float* grubi = (const float*)d_in[13];
  const float* gruWh = (const float*)d_in[14];
  const float* grubh = (const float*)d_in[15];
  const float* decW1 = (const float*)d_in[16];
  const float* decb1 = (const float*)d_in[17];
  const float* decW2 = (const float*)d_in[18];
  const float* decb2 = (const float*)d_in[19];
  const float* gWl[2]  = {(const float*)d_in[20], (const float*)d_in[27]};
  const float* gbl[2]  = {(const float*)d_in[21], (const float*)d_in[28]};
  const float* gWr[2]  = {(const float*)d_in[22], (const float*)d_in[29]};
  const float* gbr[2]  = {(const float*)d_in[23], (const float*)d_in[30]};
  const float* gWe[2]  = {(const float*)d_in[24], (const float*)d_in[31]};
  const float* gatt[2] = {(const float*)d_in[25], (const float*)d_in[32]};
  const float* gbias[2]= {(const float*)d_in[26], (const float*)d_in[33]};

  int N  = in_sizes[0] / 7;
  int E  = in_sizes[3] / 2;
  int Ea = E + N;

  char* w = (char*)d_ws;
  float* A      = (float*)w; w += (size_t)N*64*sizeof(float);   // h1 -> h2
  u16*   XL     = (u16*)w;  w += (size_t)N*64*sizeof(u16);
  u16*   XR     = (u16*)w;  w += (size_t)N*64*sizeof(u16);
  float2* msbuf1= (float2*)w; w += (size_t)N*4*sizeof(float2);
  float2* msbuf2= (float2*)w; w += (size_t)N*4*sizeof(float2);
  float4* slots = (float4*)w; w += (size_t)E*32;                // 32B per edge slot
  int*   deg    = (int*)w;   w += (size_t)N*sizeof(int);
  int*   counter= (int*)w;   w += 4*sizeof(int);
  int*   cursor = (int*)w;   w += (size_t)N*sizeof(int);
  int*   offs   = (int*)w;   w += (size_t)N*sizeof(int);

  float* out_final = (float*)d_out;
  float* out_nf    = out_final + (size_t)N*7;
  float* out_a1    = out_nf + (size_t)N*64;
  float* out_a2    = out_a1 + (size_t)Ea*4;

  // zero deg + counter (contiguous); cursor written by alloc_kernel
  hipMemsetAsync(deg, 0, ((size_t)N + 4)*sizeof(int), stream);

  deg_kernel<<<(E+1023)/1024, 256, 0, stream>>>(eidx, deg, E);
  alloc_kernel<<<(N+1023)/1024, 256, 0, stream>>>(deg, offs, cursor, counter, N);

  // enc->xfrm1 ∥ fill (enc-h never materialized)
  int exB = (N+31)/32;
  int flB = (E+1023)/1024;
  encxfill_kernel<<<exB+flB, 256, 0, stream>>>(x, pos, ntype, temb,
      encW1, encb1, encW2, encb2, gWl[0], gbl[0], gWr[0], gbr[0], XL, XR,
      eidx, eattr, cursor, slots, exB, E, N);

  // layer 1: gat; raw scores -> out_a1, (m,sinv) -> msbuf1; h1 -> A (relu)
  int gatB = (N+3)/4;
  gat_kernel<<<gatB, 256, 0, stream>>>(slots, offs, deg, XL, XR,
      gWe[0], gatt[0], gbias[0], out_a1, msbuf1, A, E, N, 1);

  // layer 2 xfrm (standalone, LDS weights)
  int xfB = (N+63)/64;
  xfrm_kernel<<<xfB, 256, 0, stream>>>(A, gWl[1], gbl[1], gWr[1], gbr[1], XL, XR, N);

  // layer 2: gat ∥ alpha1 guest blocks (front-loaded)
  int alB = (Ea+255)/256;
  gat2alpha_kernel<<<alB+gatB, 256, 0, stream>>>(slots, offs, deg, XL, XR,
      gWe[1], gatt[1], gbias[1], out_a2, msbuf2, A,
      eidx, msbuf1, (float4*)out_a1, alB, E, N, 0);

  // GRU + decoder ∥ alpha2 (range-split)
  int gdB = (N+31)/32;
  grudecalpha_kernel<<<gdB+alB, 256, 0, stream>>>(A, hid, gruWi, grubi, gruWh, grubh, Tptr,
      decW1, decb1, decW2, decb2, x, pos, out_nf, out_final,
      eidx, msbuf2, (float4*)out_a2, gdB, E, N);
}